// Round 11
// baseline (133.370 us; speedup 1.0000x reference)
//
#include <hip/hip_runtime.h>
#include <hip/hip_bf16.h>

// ---------------------------------------------------------------------------
// 2-layer GCN: out = GCN2( relu(GCN1(X)) ), GCN(x) = Dinv (A+I) Dinv (x W) + b
// Build (no global atomics, ONE edge pass for histogram):
//   k_hist: 128 chunks, 4x8-bit packed LDS counters for ALL 50k bins (50KB);
//           atomic return = local rank (uchar). Per-block dtype detect.
//           Also writes epk[e] = src|(dst<<16) so later passes never re-read
//           the 16B/edge int64 list. (blocks >= NCHUNK: W -> bf16^T, fused.)
//   k_mergescan: per-bin prefix across chunks (uchar H, 4 bins/thread) + dinv
//                + block-local row scan; k_scan3 folds the block prefix.
//   k_fill: 1 block(512 thr)/chunk, H row cached in LDS (50KB seq load);
//           csr[rowstart[dst] + Hlds[dst] + lrank[e]] = src   (reads epk only).
// Compute:
//   k_gemm1m/k_gemm2m: MFMA 16x16x32 bf16, 64-row tiles, fp32 accum,
//                      epilogue *dinv[row] -> bf16.
//   k_spmm128: HALF-wave per node (32 lanes x uint2 = 256B row), 16-deep MLP.
//   k_spmm64:  QUARTER-wave per node (16 lanes x uint2 = 128B row), 16-deep.
// ---------------------------------------------------------------------------

#define NCHUNK 128

#define OFF_ROWSTART (size_t)0x0         // (n+1) ints
#define OFF_DINV     (size_t)0x40000     // n floats
#define OFF_BLOCKSUM (size_t)0x80000     // <=64 ints
#define OFF_FLAG     (size_t)0x80800     // 1 int
#define OFF_LRANK    (size_t)0x81000     // E uchar
#define OFF_CSR      (size_t)0x150000    // E ushort
#define OFF_H        (size_t)0x300000    // NCHUNK * n uchar (6.4 MB)
#define OFF_W1T      (size_t)0xA00000    // 128x128 bf16
#define OFF_W2T      (size_t)0xA10000    // 64x128 bf16
#define OFF_BUFA     (size_t)0xB00000    // bf16 Hs1 [n][128]; later Hs2 [n][64]
#define OFF_BUFB     (size_t)0x1800000   // bf16 X1 [n][128]
#define OFF_EPK      (size_t)0x2500000   // E uint packed src|dst<<16 (3.2 MB)

typedef short bf16x8 __attribute__((ext_vector_type(8)));
typedef float f32x4 __attribute__((ext_vector_type(4)));

__device__ __forceinline__ float2 bf2f(unsigned u) {
    float2 r;
    r.x = __uint_as_float(u << 16);
    r.y = __uint_as_float(u & 0xffff0000u);
    return r;
}
__device__ __forceinline__ unsigned f2bf(float a, float b) {
    __hip_bfloat162 h = __float22bfloat162_rn(make_float2(a, b));
    union { __hip_bfloat162 h; unsigned u; } cv;
    cv.h = h;
    return cv.u;
}

// --- single-pass histogram (blocks < NCHUNK) + W conversion (blocks >=) -----
// counts per (chunk, bin) ~Poisson(0.13), max ~6 << 255: no carry.
__global__ __launch_bounds__(256) void k_hist(const int* __restrict__ e32, int E,
                                              int chunk, int n,
                                              unsigned char* __restrict__ lrank,
                                              unsigned char* __restrict__ H,
                                              unsigned* __restrict__ epk,
                                              const float* __restrict__ W1,
                                              const float* __restrict__ W2,
                                              unsigned short* __restrict__ W1T,
                                              unsigned short* __restrict__ W2T) {
    const int t = threadIdx.x, b = blockIdx.x;
    if (b >= NCHUNK) {                            // --- fused W -> bf16^T ---
        const int bb = b - NCHUNK;
        const int k0 = (t & 15) * 8;
        if (bb < 8) {                             // W1T: 128 rows of 128
            int nn = bb * 16 + (t >> 4);
            float w[8];
#pragma unroll
            for (int j = 0; j < 8; ++j) w[j] = W1[(size_t)(k0 + j) * 128 + nn];
            uint4 q;
            q.x = f2bf(w[0], w[1]); q.y = f2bf(w[2], w[3]);
            q.z = f2bf(w[4], w[5]); q.w = f2bf(w[6], w[7]);
            *reinterpret_cast<uint4*>(&W1T[(size_t)nn * 128 + k0]) = q;
        } else {                                  // W2T: 64 rows of 128
            int nn = (bb - 8) * 16 + (t >> 4);
            float w[8];
#pragma unroll
            for (int j = 0; j < 8; ++j) w[j] = W2[(size_t)(k0 + j) * 64 + nn];
            uint4 q;
            q.x = f2bf(w[0], w[1]); q.y = f2bf(w[2], w[3]);
            q.z = f2bf(w[4], w[5]); q.w = f2bf(w[6], w[7]);
            *reinterpret_cast<uint4*>(&W2T[(size_t)nn * 128 + k0]) = q;
        }
        return;
    }
    __shared__ unsigned h[12544];                // 50176 bins max
    __shared__ int anyv;
    const int nw = (n + 3) >> 2;
    if (t == 0) anyv = 0;
    for (int i = t; i < nw; i += 256) h[i] = 0u;
    __syncthreads();
    const int e0 = b * chunk, e1 = min(E, e0 + chunk);
    int v = 0;
    const int lim = min(e1, e0 + 2048);
    for (int e = e0 + t; e < lim; e += 256) v |= e32[2 * e + 1];
    if (v) atomicOr(&anyv, 1);
    __syncthreads();
    const int f = (anyv == 0) ? 1 : 0;
    for (int e = e0 + t; e < e1; e += 256) {
        int src, dst;
        if (f) { int4 w = reinterpret_cast<const int4*>(e32)[e]; src = w.x; dst = w.z; }
        else   { int2 w = reinterpret_cast<const int2*>(e32)[e]; src = w.x; dst = w.y; }
        epk[e] = (unsigned)src | ((unsigned)dst << 16);
        int sh = (dst & 3) << 3;
        unsigned old = atomicAdd(&h[dst >> 2], 1u << sh);
        lrank[e] = (unsigned char)((old >> sh) & 0xffu);
    }
    __syncthreads();
    unsigned* Hp = reinterpret_cast<unsigned*>(H);
    const size_t wbase = (size_t)b * (size_t)(n >> 2);   // n % 4 == 0
    for (int i = t; i < (n >> 2); i += 256) Hp[wbase + i] = h[i];
}

// --- merge + block scan: 1024 bins/block (4 per thread, packed uchar) -------
__global__ __launch_bounds__(256) void k_mergescan(
        unsigned char* __restrict__ H, int n,
        float* __restrict__ dinv, int* __restrict__ rowstart,
        int* __restrict__ blocksum) {
    __shared__ int sh[256];
    const int t = threadIdx.x;
    const int bin0 = blockIdx.x * 1024 + 4 * t;
    int s0 = 0, s1 = 0, s2 = 0, s3 = 0;
    if (bin0 < n) {
        unsigned* Hp = reinterpret_cast<unsigned*>(H);
        const size_t wstride = (size_t)(n >> 2);
        const size_t widx = (size_t)(bin0 >> 2);
#pragma unroll 8
        for (int b = 0; b < NCHUNK; ++b) {
            size_t idx = (size_t)b * wstride + widx;
            unsigned w = Hp[idx];
            Hp[idx] = (unsigned)s0 | ((unsigned)s1 << 8) |
                      ((unsigned)s2 << 16) | ((unsigned)s3 << 24);
            s0 += (int)(w & 0xffu);
            s1 += (int)((w >> 8) & 0xffu);
            s2 += (int)((w >> 16) & 0xffu);
            s3 += (int)((w >> 24) & 0xffu);
        }
        float4 dv;
        dv.x = rsqrtf((float)s0 + 1.0f);
        dv.y = rsqrtf((float)s1 + 1.0f);
        dv.z = rsqrtf((float)s2 + 1.0f);
        dv.w = rsqrtf((float)s3 + 1.0f);
        *reinterpret_cast<float4*>(dinv + bin0) = dv;
    }
    int tot = s0 + s1 + s2 + s3;
    sh[t] = tot;
    __syncthreads();
    for (int off = 1; off < 256; off <<= 1) {
        int add = (t >= off) ? sh[t - off] : 0;
        __syncthreads();
        sh[t] += add;
        __syncthreads();
    }
    if (bin0 < n) {
        int ex = sh[t] - tot;
        int4 rs;
        rs.x = ex;
        rs.y = ex + s0;
        rs.z = ex + s0 + s1;
        rs.w = ex + s0 + s1 + s2;
        *reinterpret_cast<int4*>(rowstart + bin0) = rs;
    }
    if (t == 255) blocksum[blockIdx.x] = sh[255];
}

// --- scan3: fold blocksum prefix (nb<=64, serial in LDS) + finalize ---------
__global__ void k_scan3(int* __restrict__ rowstart, int n,
                        const int* __restrict__ blocksum, int nb, int E) {
    __shared__ int bs[65];
    int t = threadIdx.x;
    if (t < nb) bs[t + 1] = blocksum[t];
    if (t == 0) bs[0] = 0;
    __syncthreads();
    if (t == 0) {
        int s = 0;
        for (int k = 1; k <= nb; ++k) { s += bs[k]; bs[k] = s; }
    }
    __syncthreads();
    int i = blockIdx.x * 256 + t;
    if (i < n) rowstart[i] += bs[i >> 10];
    if (i == 0) rowstart[n] = E;
}

// --- fill CSR: 1 block(512thr)/chunk, H row cached in LDS; reads epk only ---
__global__ __launch_bounds__(512) void k_fill(const unsigned* __restrict__ epk,
                                              int E, int chunk,
                                              const int* __restrict__ rowstart,
                                              const unsigned char* __restrict__ H,
                                              int n,
                                              const unsigned char* __restrict__ lrank,
                                              unsigned short* __restrict__ csr) {
    __shared__ unsigned char hs[50176];
    const int t = threadIdx.x;
    const int b = blockIdx.x;
    // load H row b (n bytes, n % 16 == 0) sequentially into LDS
    {
        const uint4* src = reinterpret_cast<const uint4*>(H + (size_t)b * n);
        uint4* dst = reinterpret_cast<uint4*>(hs);
        for (int i = t; i < (n >> 4); i += 512) dst[i] = src[i];
    }
    __syncthreads();
    const int e0 = b * chunk;
    const int e1 = min(E, e0 + chunk);
    for (int e = e0 + t; e < e1; e += 512) {
        unsigned v = epk[e];
        int src = (int)(v & 0xffffu);
        int dst = (int)(v >> 16);
        csr[rowstart[dst] + (int)hs[dst] + (int)lrank[e]] = (unsigned short)src;
    }
}

// --- GEMM1 (MFMA): [n x 128]fp32 @ W1T -> bf16 out, scaled by dinv[row] -----
__global__ __launch_bounds__(256) void k_gemm1m(const float* __restrict__ X,
                                                const unsigned short* __restrict__ W1T,
                                                const float* __restrict__ dinv,
                                                unsigned short* __restrict__ out,
                                                int n) {
    __shared__ unsigned short Xs[64 * 136];      // [row][k], pad 8
    __shared__ unsigned short Ws[128 * 136];     // [ncol][k], pad 8
    const int t = threadIdx.x;
    const int row0 = blockIdx.x * 64;
#pragma unroll
    for (int it = 0; it < 8; ++it) {             // W tile: 2048 x ushort8
        int i = t + it * 256;
        int r = i >> 4, c8 = i & 15;
        *reinterpret_cast<uint4*>(&Ws[r * 136 + c8 * 8]) =
            *reinterpret_cast<const uint4*>(&W1T[(size_t)r * 128 + c8 * 8]);
    }
#pragma unroll
    for (int it = 0; it < 8; ++it) {             // X tile: 2048 float4 -> bf16
        int i = t + it * 256;
        int r = i >> 5, c4 = i & 31;
        int gr = row0 + r;
        float4 v = make_float4(0.f, 0.f, 0.f, 0.f);
        if (gr < n) v = *reinterpret_cast<const float4*>(&X[(size_t)gr * 128 + c4 * 4]);
        uint2 q;
        q.x = f2bf(v.x, v.y);
        q.y = f2bf(v.z, v.w);
        *reinterpret_cast<uint2*>(&Xs[r * 136 + c4 * 4]) = q;
    }
    __syncthreads();
    const int w = t >> 6, lane = t & 63;
    const int m = lane & 15, kg = lane >> 4;
    f32x4 acc[8] = {};
#pragma unroll
    for (int kt = 0; kt < 128; kt += 32) {
        bf16x8 a = *reinterpret_cast<const bf16x8*>(&Xs[(w * 16 + m) * 136 + kt + kg * 8]);
#pragma unroll
        for (int j = 0; j < 8; ++j) {
            bf16x8 bb = *reinterpret_cast<const bf16x8*>(&Ws[(j * 16 + m) * 136 + kt + kg * 8]);
            acc[j] = __builtin_amdgcn_mfma_f32_16x16x32_bf16(a, bb, acc[j], 0, 0, 0);
        }
    }
    const int rbase = row0 + w * 16 + kg * 4;
#pragma unroll
    for (int r = 0; r < 4; ++r) {
        int gr = rbase + r;
        if (gr < n) {
            float dv = dinv[gr];
#pragma unroll
            for (int j = 0; j < 8; ++j)
                out[(size_t)gr * 128 + j * 16 + m] =
                    (unsigned short)(f2bf(acc[j][r] * dv, 0.f) & 0xffffu);
        }
    }
}

// --- GEMM2 (MFMA): [n x 128]bf16 @ W2T -> bf16 out, scaled by dinv[row] -----
__global__ __launch_bounds__(256) void k_gemm2m(const unsigned short* __restrict__ X1,
                                                const unsigned short* __restrict__ W2T,
                                                const float* __restrict__ dinv,
                                                unsigned short* __restrict__ out,
                                                int n) {
    __shared__ unsigned short Xs[64 * 136];
    __shared__ unsigned short Ws[64 * 136];
    const int t = threadIdx.x;
    const int row0 = blockIdx.x * 64;
#pragma unroll
    for (int it = 0; it < 4; ++it) {             // W tile: 1024 x ushort8
        int i = t + it * 256;
        int r = i >> 4, c8 = i & 15;
        *reinterpret_cast<uint4*>(&Ws[r * 136 + c8 * 8]) =
            *reinterpret_cast<const uint4*>(&W2T[(size_t)r * 128 + c8 * 8]);
    }
#pragma unroll
    for (int it = 0; it < 4; ++it) {             // X tile: 1024 x ushort8
        int i = t + it * 256;
        int r = i >> 4, c8 = i & 15;
        int gr = row0 + r;
        uint4 q = make_uint4(0u, 0u, 0u, 0u);
        if (gr < n) q = *reinterpret_cast<const uint4*>(&X1[(size_t)gr * 128 + c8 * 8]);
        *reinterpret_cast<uint4*>(&Xs[r * 136 + c8 * 8]) = q;
    }
    __syncthreads();
    const int w = t >> 6, lane = t & 63;
    const int m = lane & 15, kg = lane >> 4;
    f32x4 acc[4] = {};
#pragma unroll
    for (int kt = 0; kt < 128; kt += 32) {
        bf16x8 a = *reinterpret_cast<const bf16x8*>(&Xs[(w * 16 + m) * 136 + kt + kg * 8]);
#pragma unroll
        for (int j = 0; j < 4; ++j) {
            bf16x8 bb = *reinterpret_cast<const bf16x8*>(&Ws[(j * 16 + m) * 136 + kt + kg * 8]);
            acc[j] = __builtin_amdgcn_mfma_f32_16x16x32_bf16(a, bb, acc[j], 0, 0, 0);
        }
    }
    const int rbase = row0 + w * 16 + kg * 4;
#pragma unroll
    for (int r = 0; r < 4; ++r) {
        int gr = rbase + r;
        if (gr < n) {
            float dv = dinv[gr];
#pragma unroll
            for (int j = 0; j < 4; ++j)
                out[(size_t)gr * 64 + j * 16 + m] =
                    (unsigned short)(f2bf(acc[j][r] * dv, 0.f) & 0xffffu);
        }
    }
}

// --- SpMM, F=128: HALF-wave per node, lane = uint2 (4 bf16); 16-deep MLP ----
__global__ __launch_bounds__(256) void k_spmm128(
        const unsigned* __restrict__ H32, const int* __restrict__ rowstart,
        const unsigned short* __restrict__ csr, const float* __restrict__ dinv,
        const float* __restrict__ bias, unsigned* __restrict__ out, int n) {
    int node = blockIdx.x * 8 + (threadIdx.x >> 5);
    if (node >= n) return;
    int f2 = threadIdx.x & 31;                   // feature quad [4*f2 .. 4*f2+3]
    const uint2* H2 = reinterpret_cast<const uint2*>(H32);
    float di = dinv[node];
    uint2 sv = H2[(size_t)node * 32 + f2];       // self term (pre-scaled)
    float2 a0 = bf2f(sv.x), a1 = bf2f(sv.y);
    float acc0 = a0.x, acc1 = a0.y, acc2 = a1.x, acc3 = a1.y;
    int s0 = rowstart[node], s1 = rowstart[node + 1];
    for (int j = s0; j < s1; j += 16) {
        int srcs[16];
        uint2 uu[16];
#pragma unroll
        for (int u = 0; u < 16; ++u) srcs[u] = csr[min(j + u, s1 - 1)];
#pragma unroll
        for (int u = 0; u < 16; ++u) uu[u] = H2[(size_t)srcs[u] * 32 + f2];
#pragma unroll
        for (int u = 0; u < 16; ++u) {
            float2 f0 = bf2f(uu[u].x), f1 = bf2f(uu[u].y);
            bool ok = (j + u) < s1;
            acc0 += ok ? f0.x : 0.f;
            acc1 += ok ? f0.y : 0.f;
            acc2 += ok ? f1.x : 0.f;
            acc3 += ok ? f1.y : 0.f;
        }
    }
    float4 b = reinterpret_cast<const float4*>(bias)[f2];
    float o0 = fmaxf(fmaf(di, acc0, b.x), 0.f);
    float o1 = fmaxf(fmaf(di, acc1, b.y), 0.f);
    float o2 = fmaxf(fmaf(di, acc2, b.z), 0.f);
    float o3 = fmaxf(fmaf(di, acc3, b.w), 0.f);
    uint2 q;
    q.x = f2bf(o0, o1);
    q.y = f2bf(o2, o3);
    reinterpret_cast<uint2*>(out)[(size_t)node * 32 + f2] = q;   // X1 in bf16
}

// --- SpMM, F=64: QUARTER-wave per node, lane = uint2 (4 bf16); 16-deep ------
__global__ __launch_bounds__(256) void k_spmm64(
        const unsigned* __restrict__ H32, const int* __restrict__ rowstart,
        const unsigned short* __restrict__ csr, const float* __restrict__ dinv,
        const float* __restrict__ bias, float* __restrict__ out, int n) {
    int node = blockIdx.x * 16 + (threadIdx.x >> 4);
    if (node >= n) return;
    int f2 = threadIdx.x & 15;                   // feature quad [4*f2 .. 4*f2+3]
    const uint2* H2 = reinterpret_cast<const uint2*>(H32);
    float di = dinv[node];
    uint2 sv = H2[(size_t)node * 16 + f2];       // self term
    float2 a0 = bf2f(sv.x), a1 = bf2f(sv.y);
    float acc0 = a0.x, acc1 = a0.y, acc2 = a1.x, acc3 = a1.y;
    int s0 = rowstart[node], s1 = rowstart[node + 1];
    for (int j = s0; j < s1; j += 16) {
        int srcs[16];
        uint2 uu[16];
#pragma unroll
        for (int u = 0; u < 16; ++u) srcs[u] = csr[min(j + u, s1 - 1)];
#pragma unroll
        for (int u = 0; u < 16; ++u) uu[u] = H2[(size_t)srcs[u] * 16 + f2];
#pragma unroll
        for (int u = 0; u < 16; ++u) {
            float2 f0 = bf2f(uu[u].x), f1 = bf2f(uu[u].y);
            bool ok = (j + u) < s1;
            acc0 += ok ? f0.x : 0.f;
            acc1 += ok ? f0.y : 0.f;
            acc2 += ok ? f1.x : 0.f;
            acc3 += ok ? f1.y : 0.f;
        }
    }
    float4 b = reinterpret_cast<const float4*>(bias)[f2];
    float4 o;
    o.x = fmaf(di, acc0, b.x);
    o.y = fmaf(di, acc1, b.y);
    o.z = fmaf(di, acc2, b.z);
    o.w = fmaf(di, acc3, b.w);
    reinterpret_cast<float4*>(out)[(size_t)node * 16 + f2] = o;
}

extern "C" void kernel_launch(void* const* d_in, const int* in_sizes, int n_in,
                              void* d_out, int out_size, void* d_ws, size_t ws_size,
                              hipStream_t stream) {
    const float* X   = (const float*)d_in[0];
    const int*   e32 = (const int*)d_in[1];
    const float* W1  = (const float*)d_in[2];
    const float* b1  = (const float*)d_in[3];
    const float* W2  = (const float*)d_in[4];
    const float* b2  = (const float*)d_in[5];
    float* out = (float*)d_out;

    const int n = in_sizes[0] / 128;
    const int E = in_sizes[1] / 2;
    const int chunk = (((E + NCHUNK - 1) / NCHUNK) + 511) & ~511;  // mult of 512

    char* ws = (char*)d_ws;
    int*            rowstart = (int*)(ws + OFF_ROWSTART);
    float*          dinv     = (float*)(ws + OFF_DINV);
    int*            blocksum = (int*)(ws + OFF_BLOCKSUM);
    unsigned char*  lrank    = (unsigned char*)(ws + OFF_LRANK);
    unsigned short* csr      = (unsigned short*)(ws + OFF_CSR);
    unsigned char*  H        = (unsigned char*)(ws + OFF_H);
    unsigned short* W1T      = (unsigned short*)(ws + OFF_W1T);
    unsigned short* W2T      = (unsigned short*)(ws + OFF_W2T);
    unsigned short* bufA     = (unsigned short*)(ws + OFF_BUFA);  // Hs1/Hs2 bf16
    unsigned*       bufB     = (unsigned*)(ws + OFF_BUFB);        // X1 bf16x2
    unsigned*       epk      = (unsigned*)(ws + OFF_EPK);         // packed edges

    const int NB   = (n + 255) / 256;
    const int NBms = (n + 1023) / 1024;
    const int RB   = (n + 63) / 64;

    k_hist<<<NCHUNK + 12, 256, 0, stream>>>(e32, E, chunk, n, lrank, H, epk,
                                            W1, W2, W1T, W2T);
    k_mergescan<<<NBms, 256, 0, stream>>>(H, n, dinv, rowstart, blocksum);
    k_scan3<<<NB, 256, 0, stream>>>(rowstart, n, blocksum, NBms, E);
    k_fill<<<NCHUNK, 512, 0, stream>>>(epk, E, chunk, rowstart, H, n,
                                       lrank, csr);

    k_gemm1m<<<RB, 256, 0, stream>>>(X, W1T, dinv, bufA, n);
    k_spmm128<<<(n + 7) / 8, 256, 0, stream>>>((const unsigned*)bufA, rowstart, csr,
                                               dinv, b1, bufB, n);
    k_gemm2m<<<RB, 256, 0, stream>>>((const unsigned short*)bufB, W2T, dinv, bufA, n);
    k_spmm64<<<(n + 15) / 16, 256, 0, stream>>>((const unsigned*)bufA, rowstart, csr,
                                                dinv, b2, out, n);
}

// Round 12
// 125.586 us; speedup vs baseline: 1.0620x; 1.0620x over previous
//
#include <hip/hip_runtime.h>
#include <hip/hip_bf16.h>

// ---------------------------------------------------------------------------
// 2-layer GCN: out = GCN2( relu(GCN1(X)) ), GCN(x) = Dinv (A+I) Dinv (x W) + b
// R12 = exact revert to R10 (best measured: 126.1 us).
// Build (no global atomics, ONE edge pass for histogram):
//   k_hist: 128 chunks, 4x8-bit packed LDS counters for ALL 50k bins (50KB);
//           atomic return = local rank (uchar). Per-block dtype detect.
//           Also writes epk[e] = src|(dst<<16). (blocks >= NCHUNK: W->bf16^T.)
//   k_mergescan: per-bin prefix across chunks (uchar H, 4 bins/thread) + dinv
//                + block-local row scan; k_scan3 folds the block prefix.
//   k_fill: 2 blocks(256thr)/chunk (256 blocks = 1/CU), H row in LDS;
//           csr[rowstart[dst] + Hlds[dst] + lrank[e]] = src   (reads epk only).
// Compute:
//   k_gemm1m/k_gemm2m: MFMA 16x16x32 bf16, 64-row tiles, fp32 accum,
//                      epilogue *dinv[row] -> bf16.
//   k_spmm128: HALF-wave per node (32 lanes x uint2 = 256B row), 8-deep MLP.
//   k_spmm64:  QUARTER-wave per node (16 lanes x uint2 = 128B row), 8-deep.
// ---------------------------------------------------------------------------

#define NCHUNK 128

#define OFF_ROWSTART (size_t)0x0         // (n+1) ints
#define OFF_DINV     (size_t)0x40000     // n floats
#define OFF_BLOCKSUM (size_t)0x80000     // <=64 ints
#define OFF_FLAG     (size_t)0x80800     // 1 int
#define OFF_LRANK    (size_t)0x81000     // E uchar
#define OFF_CSR      (size_t)0x150000    // E ushort
#define OFF_H        (size_t)0x300000    // NCHUNK * n uchar (6.4 MB)
#define OFF_W1T      (size_t)0xA00000    // 128x128 bf16
#define OFF_W2T      (size_t)0xA10000    // 64x128 bf16
#define OFF_BUFA     (size_t)0xB00000    // bf16 Hs1 [n][128]; later Hs2 [n][64]
#define OFF_BUFB     (size_t)0x1800000   // bf16 X1 [n][128]
#define OFF_EPK      (size_t)0x2500000   // E uint packed src|dst<<16 (3.2 MB)

typedef short bf16x8 __attribute__((ext_vector_type(8)));
typedef float f32x4 __attribute__((ext_vector_type(4)));

__device__ __forceinline__ float2 bf2f(unsigned u) {
    float2 r;
    r.x = __uint_as_float(u << 16);
    r.y = __uint_as_float(u & 0xffff0000u);
    return r;
}
__device__ __forceinline__ unsigned f2bf(float a, float b) {
    __hip_bfloat162 h = __float22bfloat162_rn(make_float2(a, b));
    union { __hip_bfloat162 h; unsigned u; } cv;
    cv.h = h;
    return cv.u;
}

// --- single-pass histogram (blocks < NCHUNK) + W conversion (blocks >=) -----
// counts per (chunk, bin) ~Poisson(0.13), max ~6 << 255: no carry.
__global__ __launch_bounds__(256) void k_hist(const int* __restrict__ e32, int E,
                                              int chunk, int n,
                                              unsigned char* __restrict__ lrank,
                                              unsigned char* __restrict__ H,
                                              unsigned* __restrict__ epk,
                                              const float* __restrict__ W1,
                                              const float* __restrict__ W2,
                                              unsigned short* __restrict__ W1T,
                                              unsigned short* __restrict__ W2T) {
    const int t = threadIdx.x, b = blockIdx.x;
    if (b >= NCHUNK) {                            // --- fused W -> bf16^T ---
        const int bb = b - NCHUNK;
        const int k0 = (t & 15) * 8;
        if (bb < 8) {                             // W1T: 128 rows of 128
            int nn = bb * 16 + (t >> 4);
            float w[8];
#pragma unroll
            for (int j = 0; j < 8; ++j) w[j] = W1[(size_t)(k0 + j) * 128 + nn];
            uint4 q;
            q.x = f2bf(w[0], w[1]); q.y = f2bf(w[2], w[3]);
            q.z = f2bf(w[4], w[5]); q.w = f2bf(w[6], w[7]);
            *reinterpret_cast<uint4*>(&W1T[(size_t)nn * 128 + k0]) = q;
        } else {                                  // W2T: 64 rows of 128
            int nn = (bb - 8) * 16 + (t >> 4);
            float w[8];
#pragma unroll
            for (int j = 0; j < 8; ++j) w[j] = W2[(size_t)(k0 + j) * 64 + nn];
            uint4 q;
            q.x = f2bf(w[0], w[1]); q.y = f2bf(w[2], w[3]);
            q.z = f2bf(w[4], w[5]); q.w = f2bf(w[6], w[7]);
            *reinterpret_cast<uint4*>(&W2T[(size_t)nn * 128 + k0]) = q;
        }
        return;
    }
    __shared__ unsigned h[12544];                // 50176 bins max
    __shared__ int anyv;
    const int nw = (n + 3) >> 2;
    if (t == 0) anyv = 0;
    for (int i = t; i < nw; i += 256) h[i] = 0u;
    __syncthreads();
    const int e0 = b * chunk, e1 = min(E, e0 + chunk);
    int v = 0;
    const int lim = min(e1, e0 + 2048);
    for (int e = e0 + t; e < lim; e += 256) v |= e32[2 * e + 1];
    if (v) atomicOr(&anyv, 1);
    __syncthreads();
    const int f = (anyv == 0) ? 1 : 0;
    for (int e = e0 + t; e < e1; e += 256) {
        int src, dst;
        if (f) { int4 w = reinterpret_cast<const int4*>(e32)[e]; src = w.x; dst = w.z; }
        else   { int2 w = reinterpret_cast<const int2*>(e32)[e]; src = w.x; dst = w.y; }
        epk[e] = (unsigned)src | ((unsigned)dst << 16);
        int sh = (dst & 3) << 3;
        unsigned old = atomicAdd(&h[dst >> 2], 1u << sh);
        lrank[e] = (unsigned char)((old >> sh) & 0xffu);
    }
    __syncthreads();
    unsigned* Hp = reinterpret_cast<unsigned*>(H);
    const size_t wbase = (size_t)b * (size_t)(n >> 2);   // n % 4 == 0
    for (int i = t; i < (n >> 2); i += 256) Hp[wbase + i] = h[i];
}

// --- merge + block scan: 1024 bins/block (4 per thread, packed uchar) -------
__global__ __launch_bounds__(256) void k_mergescan(
        unsigned char* __restrict__ H, int n,
        float* __restrict__ dinv, int* __restrict__ rowstart,
        int* __restrict__ blocksum) {
    __shared__ int sh[256];
    const int t = threadIdx.x;
    const int bin0 = blockIdx.x * 1024 + 4 * t;
    int s0 = 0, s1 = 0, s2 = 0, s3 = 0;
    if (bin0 < n) {
        unsigned* Hp = reinterpret_cast<unsigned*>(H);
        const size_t wstride = (size_t)(n >> 2);
        const size_t widx = (size_t)(bin0 >> 2);
#pragma unroll 8
        for (int b = 0; b < NCHUNK; ++b) {
            size_t idx = (size_t)b * wstride + widx;
            unsigned w = Hp[idx];
            Hp[idx] = (unsigned)s0 | ((unsigned)s1 << 8) |
                      ((unsigned)s2 << 16) | ((unsigned)s3 << 24);
            s0 += (int)(w & 0xffu);
            s1 += (int)((w >> 8) & 0xffu);
            s2 += (int)((w >> 16) & 0xffu);
            s3 += (int)((w >> 24) & 0xffu);
        }
        float4 dv;
        dv.x = rsqrtf((float)s0 + 1.0f);
        dv.y = rsqrtf((float)s1 + 1.0f);
        dv.z = rsqrtf((float)s2 + 1.0f);
        dv.w = rsqrtf((float)s3 + 1.0f);
        *reinterpret_cast<float4*>(dinv + bin0) = dv;
    }
    int tot = s0 + s1 + s2 + s3;
    sh[t] = tot;
    __syncthreads();
    for (int off = 1; off < 256; off <<= 1) {
        int add = (t >= off) ? sh[t - off] : 0;
        __syncthreads();
        sh[t] += add;
        __syncthreads();
    }
    if (bin0 < n) {
        int ex = sh[t] - tot;
        int4 rs;
        rs.x = ex;
        rs.y = ex + s0;
        rs.z = ex + s0 + s1;
        rs.w = ex + s0 + s1 + s2;
        *reinterpret_cast<int4*>(rowstart + bin0) = rs;
    }
    if (t == 255) blocksum[blockIdx.x] = sh[255];
}

// --- scan3: fold blocksum prefix (nb<=64, serial in LDS) + finalize ---------
__global__ void k_scan3(int* __restrict__ rowstart, int n,
                        const int* __restrict__ blocksum, int nb, int E) {
    __shared__ int bs[65];
    int t = threadIdx.x;
    if (t < nb) bs[t + 1] = blocksum[t];
    if (t == 0) bs[0] = 0;
    __syncthreads();
    if (t == 0) {
        int s = 0;
        for (int k = 1; k <= nb; ++k) { s += bs[k]; bs[k] = s; }
    }
    __syncthreads();
    int i = blockIdx.x * 256 + t;
    if (i < n) rowstart[i] += bs[i >> 10];
    if (i == 0) rowstart[n] = E;
}

// --- fill CSR: 2 blocks/chunk, H row cached in LDS; reads packed epk --------
__global__ __launch_bounds__(256) void k_fill(const unsigned* __restrict__ epk,
                                              int E, int chunk,
                                              const int* __restrict__ rowstart,
                                              const unsigned char* __restrict__ H,
                                              int n,
                                              const unsigned char* __restrict__ lrank,
                                              unsigned short* __restrict__ csr) {
    __shared__ unsigned char hs[50176];
    const int t = threadIdx.x;
    const int b = blockIdx.x >> 1;
    const int half = blockIdx.x & 1;
    // load H row b (n bytes, n % 16 == 0) sequentially into LDS
    {
        const uint4* src = reinterpret_cast<const uint4*>(H + (size_t)b * n);
        uint4* dst = reinterpret_cast<uint4*>(hs);
        for (int i = t; i < (n >> 4); i += 256) dst[i] = src[i];
    }
    __syncthreads();
    const int hchunk = chunk >> 1;
    const int e0 = b * chunk + half * hchunk;
    const int e1 = min(E, e0 + hchunk);
    for (int e = e0 + t; e < e1; e += 256) {
        unsigned v = epk[e];
        int src = (int)(v & 0xffffu);
        int dst = (int)(v >> 16);
        csr[rowstart[dst] + (int)hs[dst] + (int)lrank[e]] = (unsigned short)src;
    }
}

// --- GEMM1 (MFMA): [n x 128]fp32 @ W1T -> bf16 out, scaled by dinv[row] -----
__global__ __launch_bounds__(256) void k_gemm1m(const float* __restrict__ X,
                                                const unsigned short* __restrict__ W1T,
                                                const float* __restrict__ dinv,
                                                unsigned short* __restrict__ out,
                                                int n) {
    __shared__ unsigned short Xs[64 * 136];      // [row][k], pad 8
    __shared__ unsigned short Ws[128 * 136];     // [ncol][k], pad 8
    const int t = threadIdx.x;
    const int row0 = blockIdx.x * 64;
#pragma unroll
    for (int it = 0; it < 8; ++it) {             // W tile: 2048 x ushort8
        int i = t + it * 256;
        int r = i >> 4, c8 = i & 15;
        *reinterpret_cast<uint4*>(&Ws[r * 136 + c8 * 8]) =
            *reinterpret_cast<const uint4*>(&W1T[(size_t)r * 128 + c8 * 8]);
    }
#pragma unroll
    for (int it = 0; it < 8; ++it) {             // X tile: 2048 float4 -> bf16
        int i = t + it * 256;
        int r = i >> 5, c4 = i & 31;
        int gr = row0 + r;
        float4 v = make_float4(0.f, 0.f, 0.f, 0.f);
        if (gr < n) v = *reinterpret_cast<const float4*>(&X[(size_t)gr * 128 + c4 * 4]);
        uint2 q;
        q.x = f2bf(v.x, v.y);
        q.y = f2bf(v.z, v.w);
        *reinterpret_cast<uint2*>(&Xs[r * 136 + c4 * 4]) = q;
    }
    __syncthreads();
    const int w = t >> 6, lane = t & 63;
    const int m = lane & 15, kg = lane >> 4;
    f32x4 acc[8] = {};
#pragma unroll
    for (int kt = 0; kt < 128; kt += 32) {
        bf16x8 a = *reinterpret_cast<const bf16x8*>(&Xs[(w * 16 + m) * 136 + kt + kg * 8]);
#pragma unroll
        for (int j = 0; j < 8; ++j) {
            bf16x8 bb = *reinterpret_cast<const bf16x8*>(&Ws[(j * 16 + m) * 136 + kt + kg * 8]);
            acc[j] = __builtin_amdgcn_mfma_f32_16x16x32_bf16(a, bb, acc[j], 0, 0, 0);
        }
    }
    const int rbase = row0 + w * 16 + kg * 4;
#pragma unroll
    for (int r = 0; r < 4; ++r) {
        int gr = rbase + r;
        if (gr < n) {
            float dv = dinv[gr];
#pragma unroll
            for (int j = 0; j < 8; ++j)
                out[(size_t)gr * 128 + j * 16 + m] =
                    (unsigned short)(f2bf(acc[j][r] * dv, 0.f) & 0xffffu);
        }
    }
}

// --- GEMM2 (MFMA): [n x 128]bf16 @ W2T -> bf16 out, scaled by dinv[row] -----
__global__ __launch_bounds__(256) void k_gemm2m(const unsigned short* __restrict__ X1,
                                                const unsigned short* __restrict__ W2T,
                                                const float* __restrict__ dinv,
                                                unsigned short* __restrict__ out,
                                                int n) {
    __shared__ unsigned short Xs[64 * 136];
    __shared__ unsigned short Ws[64 * 136];
    const int t = threadIdx.x;
    const int row0 = blockIdx.x * 64;
#pragma unroll
    for (int it = 0; it < 4; ++it) {             // W tile: 1024 x ushort8
        int i = t + it * 256;
        int r = i >> 4, c8 = i & 15;
        *reinterpret_cast<uint4*>(&Ws[r * 136 + c8 * 8]) =
            *reinterpret_cast<const uint4*>(&W2T[(size_t)r * 128 + c8 * 8]);
    }
#pragma unroll
    for (int it = 0; it < 4; ++it) {             // X tile: 1024 x ushort8
        int i = t + it * 256;
        int r = i >> 4, c8 = i & 15;
        int gr = row0 + r;
        uint4 q = make_uint4(0u, 0u, 0u, 0u);
        if (gr < n) q = *reinterpret_cast<const uint4*>(&X1[(size_t)gr * 128 + c8 * 8]);
        *reinterpret_cast<uint4*>(&Xs[r * 136 + c8 * 8]) = q;
    }
    __syncthreads();
    const int w = t >> 6, lane = t & 63;
    const int m = lane & 15, kg = lane >> 4;
    f32x4 acc[4] = {};
#pragma unroll
    for (int kt = 0; kt < 128; kt += 32) {
        bf16x8 a = *reinterpret_cast<const bf16x8*>(&Xs[(w * 16 + m) * 136 + kt + kg * 8]);
#pragma unroll
        for (int j = 0; j < 4; ++j) {
            bf16x8 bb = *reinterpret_cast<const bf16x8*>(&Ws[(j * 16 + m) * 136 + kt + kg * 8]);
            acc[j] = __builtin_amdgcn_mfma_f32_16x16x32_bf16(a, bb, acc[j], 0, 0, 0);
        }
    }
    const int rbase = row0 + w * 16 + kg * 4;
#pragma unroll
    for (int r = 0; r < 4; ++r) {
        int gr = rbase + r;
        if (gr < n) {
            float dv = dinv[gr];
#pragma unroll
            for (int j = 0; j < 4; ++j)
                out[(size_t)gr * 64 + j * 16 + m] =
                    (unsigned short)(f2bf(acc[j][r] * dv, 0.f) & 0xffffu);
        }
    }
}

// --- SpMM, F=128: HALF-wave per node, lane = uint2 (4 bf16); 8-deep MLP -----
__global__ __launch_bounds__(256) void k_spmm128(
        const unsigned* __restrict__ H32, const int* __restrict__ rowstart,
        const unsigned short* __restrict__ csr, const float* __restrict__ dinv,
        const float* __restrict__ bias, unsigned* __restrict__ out, int n) {
    int node = blockIdx.x * 8 + (threadIdx.x >> 5);
    if (node >= n) return;
    int f2 = threadIdx.x & 31;                   // feature quad [4*f2 .. 4*f2+3]
    const uint2* H2 = reinterpret_cast<const uint2*>(H32);
    float di = dinv[node];
    uint2 sv = H2[(size_t)node * 32 + f2];       // self term (pre-scaled)
    float2 a0 = bf2f(sv.x), a1 = bf2f(sv.y);
    float acc0 = a0.x, acc1 = a0.y, acc2 = a1.x, acc3 = a1.y;
    int s0 = rowstart[node], s1 = rowstart[node + 1];
    for (int j = s0; j < s1; j += 8) {
        int srcs[8];
        uint2 uu[8];
#pragma unroll
        for (int u = 0; u < 8; ++u) srcs[u] = csr[min(j + u, s1 - 1)];
#pragma unroll
        for (int u = 0; u < 8; ++u) uu[u] = H2[(size_t)srcs[u] * 32 + f2];
#pragma unroll
        for (int u = 0; u < 8; ++u) {
            float2 f0 = bf2f(uu[u].x), f1 = bf2f(uu[u].y);
            bool ok = (j + u) < s1;
            acc0 += ok ? f0.x : 0.f;
            acc1 += ok ? f0.y : 0.f;
            acc2 += ok ? f1.x : 0.f;
            acc3 += ok ? f1.y : 0.f;
        }
    }
    float4 b = reinterpret_cast<const float4*>(bias)[f2];
    float o0 = fmaxf(fmaf(di, acc0, b.x), 0.f);
    float o1 = fmaxf(fmaf(di, acc1, b.y), 0.f);
    float o2 = fmaxf(fmaf(di, acc2, b.z), 0.f);
    float o3 = fmaxf(fmaf(di, acc3, b.w), 0.f);
    uint2 q;
    q.x = f2bf(o0, o1);
    q.y = f2bf(o2, o3);
    reinterpret_cast<uint2*>(out)[(size_t)node * 32 + f2] = q;   // X1 in bf16
}

// --- SpMM, F=64: QUARTER-wave per node, lane = uint2 (4 bf16); out fp32 -----
__global__ __launch_bounds__(256) void k_spmm64(
        const unsigned* __restrict__ H32, const int* __restrict__ rowstart,
        const unsigned short* __restrict__ csr, const float* __restrict__ dinv,
        const float* __restrict__ bias, float* __restrict__ out, int n) {
    int node = blockIdx.x * 16 + (threadIdx.x >> 4);
    if (node >= n) return;
    int f2 = threadIdx.x & 15;                   // feature quad [4*f2 .. 4*f2+3]
    const uint2* H2 = reinterpret_cast<const uint2*>(H32);
    float di = dinv[node];
    uint2 sv = H2[(size_t)node * 16 + f2];       // self term
    float2 a0 = bf2f(sv.x), a1 = bf2f(sv.y);
    float acc0 = a0.x, acc1 = a0.y, acc2 = a1.x, acc3 = a1.y;
    int s0 = rowstart[node], s1 = rowstart[node + 1];
    for (int j = s0; j < s1; j += 8) {
        int srcs[8];
        uint2 uu[8];
#pragma unroll
        for (int u = 0; u < 8; ++u) srcs[u] = csr[min(j + u, s1 - 1)];
#pragma unroll
        for (int u = 0; u < 8; ++u) uu[u] = H2[(size_t)srcs[u] * 16 + f2];
#pragma unroll
        for (int u = 0; u < 8; ++u) {
            float2 f0 = bf2f(uu[u].x), f1 = bf2f(uu[u].y);
            bool ok = (j + u) < s1;
            acc0 += ok ? f0.x : 0.f;
            acc1 += ok ? f0.y : 0.f;
            acc2 += ok ? f1.x : 0.f;
            acc3 += ok ? f1.y : 0.f;
        }
    }
    float4 b = reinterpret_cast<const float4*>(bias)[f2];
    float4 o;
    o.x = fmaf(di, acc0, b.x);
    o.y = fmaf(di, acc1, b.y);
    o.z = fmaf(di, acc2, b.z);
    o.w = fmaf(di, acc3, b.w);
    reinterpret_cast<float4*>(out)[(size_t)node * 16 + f2] = o;
}

extern "C" void kernel_launch(void* const* d_in, const int* in_sizes, int n_in,
                              void* d_out, int out_size, void* d_ws, size_t ws_size,
                              hipStream_t stream) {
    const float* X   = (const float*)d_in[0];
    const int*   e32 = (const int*)d_in[1];
    const float* W1  = (const float*)d_in[2];
    const float* b1  = (const float*)d_in[3];
    const float* W2  = (const float*)d_in[4];
    const float* b2  = (const float*)d_in[5];
    float* out = (float*)d_out;

    const int n = in_sizes[0] / 128;
    const int E = in_sizes[1] / 2;
    const int chunk = (((E + NCHUNK - 1) / NCHUNK) + 511) & ~511;  // mult of 512

    char* ws = (char*)d_ws;
    int*            rowstart = (int*)(ws + OFF_ROWSTART);
    float*          dinv     = (float*)(ws + OFF_DINV);
    int*            blocksum = (int*)(ws + OFF_BLOCKSUM);
    unsigned char*  lrank    = (unsigned char*)(ws + OFF_LRANK);
    unsigned short* csr      = (unsigned short*)(ws + OFF_CSR);
    unsigned char*  H        = (unsigned char*)(ws + OFF_H);
    unsigned short* W1T      = (unsigned short*)(ws + OFF_W1T);
    unsigned short* W2T      = (unsigned short*)(ws + OFF_W2T);
    unsigned short* bufA     = (unsigned short*)(ws + OFF_BUFA);  // Hs1/Hs2 bf16
    unsigned*       bufB     = (unsigned*)(ws + OFF_BUFB);        // X1 bf16x2
    unsigned*       epk      = (unsigned*)(ws + OFF_EPK);         // packed edges

    const int NB   = (n + 255) / 256;
    const int NBms = (n + 1023) / 1024;
    const int RB   = (n + 63) / 64;

    k_hist<<<NCHUNK + 12, 256, 0, stream>>>(e32, E, chunk, n, lrank, H, epk,
                                            W1, W2, W1T, W2T);
    k_mergescan<<<NBms, 256, 0, stream>>>(H, n, dinv, rowstart, blocksum);
    k_scan3<<<NB, 256, 0, stream>>>(rowstart, n, blocksum, NBms, E);
    k_fill<<<NCHUNK * 2, 256, 0, stream>>>(epk, E, chunk, rowstart, H, n,
                                           lrank, csr);

    k_gemm1m<<<RB, 256, 0, stream>>>(X, W1T, dinv, bufA, n);
    k_spmm128<<<(n + 7) / 8, 256, 0, stream>>>((const unsigned*)bufA, rowstart, csr,
                                               dinv, b1, bufB, n);
    k_gemm2m<<<RB, 256, 0, stream>>>((const unsigned short*)bufB, W2T, dinv, bufA, n);
    k_spmm64<<<(n + 15) / 16, 256, 0, stream>>>((const unsigned*)bufA, rowstart, csr,
                                                dinv, b2, out, n);
}